// Round 4
// baseline (402.412 us; speedup 1.0000x reference)
//
#include <hip/hip_runtime.h>
#include <math.h>

#define N_ROWS 32768
#define K_CODES 4096
#define DIM 64
#define SPLITS 8
#define TILES_TOTAL (K_CODES / 32)              // 128
#define TILES_PER_SPLIT (TILES_TOTAL / SPLITS)  // 16
#define PHASES (TILES_PER_SPLIT / 2)            // 8 (2 tiles per phase)
#define QUANT_ELEMS (N_ROWS * DIM)              // 2097152

typedef _Float16 half8 __attribute__((ext_vector_type(8)));
typedef float floatx16 __attribute__((ext_vector_type(16)));

// async global->LDS, 16 B per lane (wave-uniform base + lane*16 layout)
__device__ __forceinline__ void gld16(const void* g, void* l) {
    __builtin_amdgcn_global_load_lds(
        (const __attribute__((address_space(1))) unsigned int*)g,
        (__attribute__((address_space(3))) unsigned int*)l, 16, 0, 0);
}

// ---------------------------------------------------------------------------
// Kernel 0 (fused): embed -> fp16 hi/lo B-fragments for mfma_f32_32x32x16_f16
// AND per-code squared norms (LDS reduction) AND zero-init of the per-row
// argmax keys (grid is exactly N_ROWS threads).
// Tile c = 32 codes; kstep s covers k=16s..16s+15. Thread t = c*256 + s*64 + l
// holds B[k=(l>>5)*8+j+16s][col=l&31] = embed[c*32+(l&31)][(l>>5)*8+j+16s].
// One 256-thread block per tile (grid = 128 blocks).
// ---------------------------------------------------------------------------
__global__ void prep_kernel(const float* __restrict__ embed,
                            float* __restrict__ sq, half8* __restrict__ ehi,
                            half8* __restrict__ elo,
                            unsigned long long* __restrict__ keys) {
    __shared__ float part[256];
    const int tid = threadIdx.x;
    const int t = blockIdx.x * 256 + tid;
    keys[t] = 0ull;  // any finite packed key beats 0
    const int l = t & 63;
    const int s = (t >> 6) & 3;
    const int c = blockIdx.x;  // == t >> 8
    const int col = l & 31;
    const int code = c * 32 + col;
    const int koff = (l >> 5) * 8 + 16 * s;
    const float* src = embed + (size_t)code * DIM + koff;
    half8 h, lo;
    float ss = 0.f;
#pragma unroll
    for (int j = 0; j < 8; ++j) {
        float v = src[j];
        ss = fmaf(v, v, ss);
        _Float16 hi = (_Float16)v;
        h[j] = hi;
        lo[j] = (_Float16)(v - (float)hi);
    }
    ehi[t] = h;
    elo[t] = lo;
    part[tid] = ss;
    __syncthreads();
    if (tid < 32) {
        // code (c*32 + tid)'s 8 partials live at tid + 32*h + 64*s
        float a = 0.f;
#pragma unroll
        for (int q = 0; q < 8; ++q) a += part[tid + 32 * (q & 1) + 64 * (q >> 1)];
        sq[c * 32 + tid] = a;
    }
}

// ---------------------------------------------------------------------------
// Kernel 1: fused dist(GEMM 32x32x16) + per-split argmax.
// v5 = v3's M=64 register blocking (each B ds_read_b128 feeds 24 MFMAs per
// 8 reads, ds:MFMA cycle ratio 0.49) + v2's occupancy restored via SPLITS=8:
// grid (128,8) = 1024 blocks = 4 blocks/CU = 16 waves/CU (v3 died at 2
// blocks/CU, Occupancy 21%). Pipe demands per CU: MFMA 20.6us, LDS-read
// 10.3us, VALU ~5us -> MFMA-bound if overlap works.
// Double-buffered 16 KB LDS phases (2 tiles/phase), prefetch-before-compute,
// one {s_waitcnt vmcnt(0); s_barrier} per phase.
// Cross-split/cross-wave argmax combine via packed-key atomicMax:
// key = monotone_u32(dist) << 32 | ~idx  (equal dist -> smaller idx wins,
// matching reference first-match tie semantics exactly).
// dist = dot(2x,e) - ||e||^2 ; -||e||^2 = acc init, 2x folded into A (exact).
// fp16 split, 3 terms: xh*eh + xl*eh + xh*el.
// ---------------------------------------------------------------------------
#define SUBTILE(LH, LL, NSQ, CIDX)                                           \
    {                                                                        \
        const half8* lh = (const half8*)(LH);                                \
        const half8* ll = (const half8*)(LL);                                \
        floatx16 a0, a1;                                                     \
        _Pragma("unroll") for (int r = 0; r < 16; ++r) {                     \
            a0[r] = (NSQ);                                                   \
            a1[r] = (NSQ);                                                   \
        }                                                                    \
        half8 b;                                                             \
        __builtin_amdgcn_s_setprio(1);                                       \
        b = lh[lane];                                                        \
        a0 = __builtin_amdgcn_mfma_f32_32x32x16_f16(ah[0], b, a0, 0, 0, 0);  \
        a1 = __builtin_amdgcn_mfma_f32_32x32x16_f16(ah[4], b, a1, 0, 0, 0);  \
        a0 = __builtin_amdgcn_mfma_f32_32x32x16_f16(al[0], b, a0, 0, 0, 0);  \
        a1 = __builtin_amdgcn_mfma_f32_32x32x16_f16(al[4], b, a1, 0, 0, 0);  \
        b = lh[64 + lane];                                                   \
        a0 = __builtin_amdgcn_mfma_f32_32x32x16_f16(ah[1], b, a0, 0, 0, 0);  \
        a1 = __builtin_amdgcn_mfma_f32_32x32x16_f16(ah[5], b, a1, 0, 0, 0);  \
        a0 = __builtin_amdgcn_mfma_f32_32x32x16_f16(al[1], b, a0, 0, 0, 0);  \
        a1 = __builtin_amdgcn_mfma_f32_32x32x16_f16(al[5], b, a1, 0, 0, 0);  \
        b = lh[128 + lane];                                                  \
        a0 = __builtin_amdgcn_mfma_f32_32x32x16_f16(ah[2], b, a0, 0, 0, 0);  \
        a1 = __builtin_amdgcn_mfma_f32_32x32x16_f16(ah[6], b, a1, 0, 0, 0);  \
        a0 = __builtin_amdgcn_mfma_f32_32x32x16_f16(al[2], b, a0, 0, 0, 0);  \
        a1 = __builtin_amdgcn_mfma_f32_32x32x16_f16(al[6], b, a1, 0, 0, 0);  \
        b = lh[192 + lane];                                                  \
        a0 = __builtin_amdgcn_mfma_f32_32x32x16_f16(ah[3], b, a0, 0, 0, 0);  \
        a1 = __builtin_amdgcn_mfma_f32_32x32x16_f16(ah[7], b, a1, 0, 0, 0);  \
        a0 = __builtin_amdgcn_mfma_f32_32x32x16_f16(al[3], b, a0, 0, 0, 0);  \
        a1 = __builtin_amdgcn_mfma_f32_32x32x16_f16(al[7], b, a1, 0, 0, 0);  \
        b = ll[lane];                                                        \
        a0 = __builtin_amdgcn_mfma_f32_32x32x16_f16(ah[0], b, a0, 0, 0, 0);  \
        a1 = __builtin_amdgcn_mfma_f32_32x32x16_f16(ah[4], b, a1, 0, 0, 0);  \
        b = ll[64 + lane];                                                   \
        a0 = __builtin_amdgcn_mfma_f32_32x32x16_f16(ah[1], b, a0, 0, 0, 0);  \
        a1 = __builtin_amdgcn_mfma_f32_32x32x16_f16(ah[5], b, a1, 0, 0, 0);  \
        b = ll[128 + lane];                                                  \
        a0 = __builtin_amdgcn_mfma_f32_32x32x16_f16(ah[2], b, a0, 0, 0, 0);  \
        a1 = __builtin_amdgcn_mfma_f32_32x32x16_f16(ah[6], b, a1, 0, 0, 0);  \
        b = ll[192 + lane];                                                  \
        a0 = __builtin_amdgcn_mfma_f32_32x32x16_f16(ah[3], b, a0, 0, 0, 0);  \
        a1 = __builtin_amdgcn_mfma_f32_32x32x16_f16(ah[7], b, a1, 0, 0, 0);  \
        __builtin_amdgcn_s_setprio(0);                                       \
        const int cidx = (CIDX);                                             \
        _Pragma("unroll") for (int r = 0; r < 16; ++r) {                     \
            if (a0[r] > best[r]) { /* strict >: earliest tile wins ties */   \
                best[r] = a0[r];                                             \
                bidx[r] = cidx;                                              \
            }                                                                \
            if (a1[r] > best[16 + r]) {                                      \
                best[16 + r] = a1[r];                                        \
                bidx[16 + r] = cidx;                                         \
            }                                                                \
        }                                                                    \
    }

__global__ __launch_bounds__(256, 4) void fused_dist_argmax64(
    const float* __restrict__ x, const float* __restrict__ sq,
    const half8* __restrict__ ehi, const half8* __restrict__ elo,
    unsigned long long* __restrict__ keys) {
    // two 16 KB phase buffers; within a buffer:
    // [0,4K)=hi(tile 2p) [4K,8K)=lo(2p) [8K,12K)=hi(2p+1) [12K,16K)=lo(2p+1)
    __shared__ __align__(16) char lbuf[2][16384];
    const int tid = threadIdx.x;
    const int lane = tid & 63;
    const int wave = tid >> 6;
    const int col = lane & 31;    // B col (code within tile); A row within group
    const int half_ = lane >> 5;  // k-half
    const int row_base = blockIdx.x * 256 + wave * 64;
    const int split = blockIdx.y;
    const int c0 = split * TILES_PER_SPLIT;

    // Persistent A fragments (scaled by 2), two 32-row groups:
    // group g rows = row_base + g*32 + col; A[m=col][k=half_*8+j+16s]
    half8 ah[8], al[8];
#pragma unroll
    for (int g = 0; g < 2; ++g) {
        const float* xs =
            x + (size_t)(row_base + g * 32 + col) * DIM + half_ * 8;
#pragma unroll
        for (int s = 0; s < 4; ++s) {
            half8 h, lo;
#pragma unroll
            for (int j = 0; j < 8; ++j) {
                float v = 2.0f * xs[16 * s + j];
                _Float16 hi = (_Float16)v;
                h[j] = hi;
                lo[j] = (_Float16)(v - (float)hi);
            }
            ah[g * 4 + s] = h;
            al[g * 4 + s] = lo;
        }
    }

    float best[32];
    int bidx[32];
#pragma unroll
    for (int r = 0; r < 32; ++r) {
        best[r] = -INFINITY;
        bidx[r] = 0;
    }

    const char* gh = (const char*)(ehi + (size_t)c0 * 256);
    const char* gl = (const char*)(elo + (size_t)c0 * 256);
    const float* psq = sq + c0 * 32 + col;

    // --- prologue: stage phase 0 (tiles 0,1) into lbuf[0] ---
    {
        char* d = lbuf[0];
        gld16(gh + (size_t)tid * 16, d + tid * 16);
        gld16(gl + (size_t)tid * 16, d + 4096 + tid * 16);
        gld16(gh + 4096 + (size_t)tid * 16, d + 8192 + tid * 16);
        gld16(gl + 4096 + (size_t)tid * 16, d + 12288 + tid * 16);
    }
    float nsqA = -psq[0];
    float nsqB = -psq[32];
    asm volatile("s_waitcnt vmcnt(0)" ::: "memory");
    __builtin_amdgcn_s_barrier();
    asm volatile("" ::: "memory");

    for (int p = 0; p < PHASES; ++p) {
        char* bufc = lbuf[p & 1];
        // prefetch phase p+1 into the other buffer (safe: barrier at end of
        // phase p-1 guarantees all waves finished reading it)
        if (p + 1 < PHASES) {
            char* bufn = lbuf[(p & 1) ^ 1];
            const size_t go = (size_t)(2 * p + 2) * 4096;
            gld16(gh + go + (size_t)tid * 16, bufn + tid * 16);
            gld16(gl + go + (size_t)tid * 16, bufn + 4096 + tid * 16);
            gld16(gh + go + 4096 + (size_t)tid * 16, bufn + 8192 + tid * 16);
            gld16(gl + go + 4096 + (size_t)tid * 16, bufn + 12288 + tid * 16);
        }
        const float nsq0 = nsqA, nsq1 = nsqB;
        if (p + 1 < PHASES) {
            nsqA = -psq[(2 * p + 2) * 32];
            nsqB = -psq[(2 * p + 3) * 32];
        }

        SUBTILE(bufc, bufc + 4096, nsq0, (c0 + 2 * p) * 32 + col);
        SUBTILE(bufc + 8192, bufc + 12288, nsq1, (c0 + 2 * p + 1) * 32 + col);

        // single per-phase sync: drain this phase's prefetch (issued ~48
        // MFMAs ago -> latency hidden), then release buffers to all waves.
        asm volatile("s_waitcnt vmcnt(0)" ::: "memory");
        __builtin_amdgcn_s_barrier();
        asm volatile("" ::: "memory");
    }

    // C/D layout (32x32): col = lane&31, row = (r&3) + 8*(r>>2) + 4*half_.
    // Slot r<16 -> row group 0, r>=16 -> +32.
#pragma unroll
    for (int r = 0; r < 32; ++r) {
        float bv = best[r];
        int bi = bidx[r];
#pragma unroll
        for (int d = 1; d < 32; d <<= 1) {
            float ov = __shfl_xor(bv, d);
            int oi = __shfl_xor(bi, d);
            if (ov > bv || (ov == bv && oi < bi)) {  // smaller idx on tie
                bv = ov;
                bi = oi;
            }
        }
        if (col == 0) {
            const int rr = r & 15;
            const int row = row_base + (r >> 4) * 32 + (rr & 3) +
                            8 * (rr >> 2) + 4 * half_;
            // monotone f32 -> u32 map (order-preserving incl. negatives)
            unsigned ub = __float_as_uint(bv);
            unsigned mapped = ub ^ (((int)ub >> 31) | 0x80000000u);
            unsigned long long key =
                ((unsigned long long)mapped << 32) | (unsigned)(~bi);
            atomicMax(keys + row, key);  // equal dist -> larger ~bi = min bi
        }
    }
}

// ---------------------------------------------------------------------------
// Kernel 2: read per-row key, gather quantize row, write index-as-float.
// One thread per (row, float4-chunk): t in [0, N_ROWS*16).
// ---------------------------------------------------------------------------
__global__ void combine_kernel(const unsigned long long* __restrict__ keys,
                               const float* __restrict__ embed,
                               float* __restrict__ out) {
    const int t = blockIdx.x * blockDim.x + threadIdx.x;
    const int row = t >> 4;
    const int q = t & 15;
    if (row >= N_ROWS) return;

    const unsigned long long key = keys[row];
    const int bi = (int)(~(unsigned)key);  // low32 stored as ~idx

    const float4* e4 = reinterpret_cast<const float4*>(embed);
    float4 v = e4[(size_t)bi * (DIM / 4) + q];
    reinterpret_cast<float4*>(out)[(size_t)row * (DIM / 4) + q] = v;
    if (q == 0) {
        out[(size_t)QUANT_ELEMS + row] = (float)bi;  // index as float
    }
}

// ---------------------------------------------------------------------------
extern "C" void kernel_launch(void* const* d_in, const int* in_sizes, int n_in,
                              void* d_out, int out_size, void* d_ws,
                              size_t ws_size, hipStream_t stream) {
    const float* x = (const float*)d_in[0];
    const float* embed = (const float*)d_in[1];
    float* out = (float*)d_out;

    // ws: sq 16KB | ehi 512KB | elo 512KB | keys 256KB   (total ~1.28 MB)
    char* ws = (char*)d_ws;
    float* sq = (float*)ws;
    half8* ehi = (half8*)(ws + 16384);
    half8* elo = (half8*)(ws + 16384 + 524288);
    unsigned long long* keys =
        (unsigned long long*)(ws + 16384 + 2 * 524288);

    prep_kernel<<<TILES_TOTAL, 256, 0, stream>>>(embed, sq, ehi, elo, keys);

    dim3 grid(N_ROWS / 256, SPLITS);
    fused_dist_argmax64<<<grid, 256, 0, stream>>>(x, sq, ehi, elo, keys);

    const int combine_threads = N_ROWS * (DIM / 4);
    combine_kernel<<<(combine_threads + 255) / 256, 256, 0, stream>>>(
        keys, embed, out);
}

// Round 5
// 254.599 us; speedup vs baseline: 1.5806x; 1.5806x over previous
//
#include <hip/hip_runtime.h>
#include <math.h>

#define N_ROWS 32768
#define K_CODES 4096
#define DIM 64
#define SPLITS 8
#define TILES_TOTAL (K_CODES / 32)              // 128
#define TILES_PER_SPLIT (TILES_TOTAL / SPLITS)  // 16
#define PHASES (TILES_PER_SPLIT / 2)            // 8 (2 tiles per phase)
#define QUANT_ELEMS (N_ROWS * DIM)              // 2097152

typedef _Float16 half8 __attribute__((ext_vector_type(8)));
typedef float floatx16 __attribute__((ext_vector_type(16)));

// async global->LDS, 16 B per lane (wave-uniform base + lane*16 layout)
__device__ __forceinline__ void gld16(const void* g, void* l) {
    __builtin_amdgcn_global_load_lds(
        (const __attribute__((address_space(1))) unsigned int*)g,
        (__attribute__((address_space(3))) unsigned int*)l, 16, 0, 0);
}

// ---------------------------------------------------------------------------
// Kernel 0 (fused): embed -> fp16 hi/lo B-fragments for mfma_f32_32x32x16_f16
// AND per-code squared norms (LDS reduction) AND zero-init of the per-row
// argmax keys (grid is exactly N_ROWS threads).
// Tile c = 32 codes; kstep s covers k=16s..16s+15. Thread t = c*256 + s*64 + l
// holds B[k=(l>>5)*8+j+16s][col=l&31] = embed[c*32+(l&31)][(l>>5)*8+j+16s].
// One 256-thread block per tile (grid = 128 blocks).
// ---------------------------------------------------------------------------
__global__ void prep_kernel(const float* __restrict__ embed,
                            float* __restrict__ sq, half8* __restrict__ ehi,
                            half8* __restrict__ elo,
                            unsigned long long* __restrict__ keys) {
    __shared__ float part[256];
    const int tid = threadIdx.x;
    const int t = blockIdx.x * 256 + tid;
    keys[t] = 0ull;  // any finite packed key beats 0
    const int l = t & 63;
    const int s = (t >> 6) & 3;
    const int c = blockIdx.x;  // == t >> 8
    const int col = l & 31;
    const int code = c * 32 + col;
    const int koff = (l >> 5) * 8 + 16 * s;
    const float* src = embed + (size_t)code * DIM + koff;
    half8 h, lo;
    float ss = 0.f;
#pragma unroll
    for (int j = 0; j < 8; ++j) {
        float v = src[j];
        ss = fmaf(v, v, ss);
        _Float16 hi = (_Float16)v;
        h[j] = hi;
        lo[j] = (_Float16)(v - (float)hi);
    }
    ehi[t] = h;
    elo[t] = lo;
    part[tid] = ss;
    __syncthreads();
    if (tid < 32) {
        // code (c*32 + tid)'s 8 partials live at tid + 32*h + 64*s
        float a = 0.f;
#pragma unroll
        for (int q = 0; q < 8; ++q) a += part[tid + 32 * (q & 1) + 64 * (q >> 1)];
        sq[c * 32 + tid] = a;
    }
}

// ---------------------------------------------------------------------------
// Kernel 1: fused dist(GEMM 32x32x16) + per-split argmax.
// v6 = v5 with __launch_bounds__(256,3). M=64 needs ~168 unified VGPR+AGPR
// (v3 compiled it spill-free as 104 arch + ~64 acc at an uncapped budget);
// v5's (256,4) cap of 128 forced 1.2 GB of scratch traffic. Cap 512/3=170
// fits the observed 168 -> no spill, 3 waves/SIMD = 12 waves/CU.
// Each B ds_read_b128 feeds 6 MFMAs (24 MFMA / 8 reads per tile): per-CU
// pipe demands MFMA 20.6us, LDS-read 10.3us, VALU ~5us -> MFMA-dominant.
// SPLITS=8 keeps grid at 1024 blocks (>=3 blocks/CU feedable).
// Double-buffered 16 KB LDS phases (2 tiles/phase), prefetch-before-compute,
// one {s_waitcnt vmcnt(0); s_barrier} per phase.
// Cross-split/cross-wave argmax combine via packed-key atomicMax:
// key = monotone_u32(dist) << 32 | ~idx  (equal dist -> smaller idx wins,
// matching reference first-match tie semantics exactly).
// dist = dot(2x,e) - ||e||^2 ; -||e||^2 = acc init, 2x folded into A (exact).
// fp16 split, 3 terms: xh*eh + xl*eh + xh*el.
// ---------------------------------------------------------------------------
#define SUBTILE(LH, LL, NSQ, CIDX)                                           \
    {                                                                        \
        const half8* lh = (const half8*)(LH);                                \
        const half8* ll = (const half8*)(LL);                                \
        floatx16 a0, a1;                                                     \
        _Pragma("unroll") for (int r = 0; r < 16; ++r) {                     \
            a0[r] = (NSQ);                                                   \
            a1[r] = (NSQ);                                                   \
        }                                                                    \
        half8 b;                                                             \
        __builtin_amdgcn_s_setprio(1);                                       \
        b = lh[lane];                                                        \
        a0 = __builtin_amdgcn_mfma_f32_32x32x16_f16(ah[0], b, a0, 0, 0, 0);  \
        a1 = __builtin_amdgcn_mfma_f32_32x32x16_f16(ah[4], b, a1, 0, 0, 0);  \
        a0 = __builtin_amdgcn_mfma_f32_32x32x16_f16(al[0], b, a0, 0, 0, 0);  \
        a1 = __builtin_amdgcn_mfma_f32_32x32x16_f16(al[4], b, a1, 0, 0, 0);  \
        b = lh[64 + lane];                                                   \
        a0 = __builtin_amdgcn_mfma_f32_32x32x16_f16(ah[1], b, a0, 0, 0, 0);  \
        a1 = __builtin_amdgcn_mfma_f32_32x32x16_f16(ah[5], b, a1, 0, 0, 0);  \
        a0 = __builtin_amdgcn_mfma_f32_32x32x16_f16(al[1], b, a0, 0, 0, 0);  \
        a1 = __builtin_amdgcn_mfma_f32_32x32x16_f16(al[5], b, a1, 0, 0, 0);  \
        b = lh[128 + lane];                                                  \
        a0 = __builtin_amdgcn_mfma_f32_32x32x16_f16(ah[2], b, a0, 0, 0, 0);  \
        a1 = __builtin_amdgcn_mfma_f32_32x32x16_f16(ah[6], b, a1, 0, 0, 0);  \
        a0 = __builtin_amdgcn_mfma_f32_32x32x16_f16(al[2], b, a0, 0, 0, 0);  \
        a1 = __builtin_amdgcn_mfma_f32_32x32x16_f16(al[6], b, a1, 0, 0, 0);  \
        b = lh[192 + lane];                                                  \
        a0 = __builtin_amdgcn_mfma_f32_32x32x16_f16(ah[3], b, a0, 0, 0, 0);  \
        a1 = __builtin_amdgcn_mfma_f32_32x32x16_f16(ah[7], b, a1, 0, 0, 0);  \
        a0 = __builtin_amdgcn_mfma_f32_32x32x16_f16(al[3], b, a0, 0, 0, 0);  \
        a1 = __builtin_amdgcn_mfma_f32_32x32x16_f16(al[7], b, a1, 0, 0, 0);  \
        b = ll[lane];                                                        \
        a0 = __builtin_amdgcn_mfma_f32_32x32x16_f16(ah[0], b, a0, 0, 0, 0);  \
        a1 = __builtin_amdgcn_mfma_f32_32x32x16_f16(ah[4], b, a1, 0, 0, 0);  \
        b = ll[64 + lane];                                                   \
        a0 = __builtin_amdgcn_mfma_f32_32x32x16_f16(ah[1], b, a0, 0, 0, 0);  \
        a1 = __builtin_amdgcn_mfma_f32_32x32x16_f16(ah[5], b, a1, 0, 0, 0);  \
        b = ll[128 + lane];                                                  \
        a0 = __builtin_amdgcn_mfma_f32_32x32x16_f16(ah[2], b, a0, 0, 0, 0);  \
        a1 = __builtin_amdgcn_mfma_f32_32x32x16_f16(ah[6], b, a1, 0, 0, 0);  \
        b = ll[192 + lane];                                                  \
        a0 = __builtin_amdgcn_mfma_f32_32x32x16_f16(ah[3], b, a0, 0, 0, 0);  \
        a1 = __builtin_amdgcn_mfma_f32_32x32x16_f16(ah[7], b, a1, 0, 0, 0);  \
        __builtin_amdgcn_s_setprio(0);                                       \
        const int cidx = (CIDX);                                             \
        _Pragma("unroll") for (int r = 0; r < 16; ++r) {                     \
            if (a0[r] > best[r]) { /* strict >: earliest tile wins ties */   \
                best[r] = a0[r];                                             \
                bidx[r] = cidx;                                              \
            }                                                                \
            if (a1[r] > best[16 + r]) {                                      \
                best[16 + r] = a1[r];                                        \
                bidx[16 + r] = cidx;                                         \
            }                                                                \
        }                                                                    \
    }

__global__ __launch_bounds__(256, 3) void fused_dist_argmax64(
    const float* __restrict__ x, const float* __restrict__ sq,
    const half8* __restrict__ ehi, const half8* __restrict__ elo,
    unsigned long long* __restrict__ keys) {
    // two 16 KB phase buffers; within a buffer:
    // [0,4K)=hi(tile 2p) [4K,8K)=lo(2p) [8K,12K)=hi(2p+1) [12K,16K)=lo(2p+1)
    __shared__ __align__(16) char lbuf[2][16384];
    const int tid = threadIdx.x;
    const int lane = tid & 63;
    const int wave = tid >> 6;
    const int col = lane & 31;    // B col (code within tile); A row within group
    const int half_ = lane >> 5;  // k-half
    const int row_base = blockIdx.x * 256 + wave * 64;
    const int split = blockIdx.y;
    const int c0 = split * TILES_PER_SPLIT;

    // Persistent A fragments (scaled by 2), two 32-row groups:
    // group g rows = row_base + g*32 + col; A[m=col][k=half_*8+j+16s]
    half8 ah[8], al[8];
#pragma unroll
    for (int g = 0; g < 2; ++g) {
        const float* xs =
            x + (size_t)(row_base + g * 32 + col) * DIM + half_ * 8;
#pragma unroll
        for (int s = 0; s < 4; ++s) {
            half8 h, lo;
#pragma unroll
            for (int j = 0; j < 8; ++j) {
                float v = 2.0f * xs[16 * s + j];
                _Float16 hi = (_Float16)v;
                h[j] = hi;
                lo[j] = (_Float16)(v - (float)hi);
            }
            ah[g * 4 + s] = h;
            al[g * 4 + s] = lo;
        }
    }

    float best[32];
    int bidx[32];
#pragma unroll
    for (int r = 0; r < 32; ++r) {
        best[r] = -INFINITY;
        bidx[r] = 0;
    }

    const char* gh = (const char*)(ehi + (size_t)c0 * 256);
    const char* gl = (const char*)(elo + (size_t)c0 * 256);
    const float* psq = sq + c0 * 32 + col;

    // --- prologue: stage phase 0 (tiles 0,1) into lbuf[0] ---
    {
        char* d = lbuf[0];
        gld16(gh + (size_t)tid * 16, d + tid * 16);
        gld16(gl + (size_t)tid * 16, d + 4096 + tid * 16);
        gld16(gh + 4096 + (size_t)tid * 16, d + 8192 + tid * 16);
        gld16(gl + 4096 + (size_t)tid * 16, d + 12288 + tid * 16);
    }
    float nsqA = -psq[0];
    float nsqB = -psq[32];
    asm volatile("s_waitcnt vmcnt(0)" ::: "memory");
    __builtin_amdgcn_s_barrier();
    asm volatile("" ::: "memory");

    for (int p = 0; p < PHASES; ++p) {
        char* bufc = lbuf[p & 1];
        // prefetch phase p+1 into the other buffer (safe: barrier at end of
        // phase p-1 guarantees all waves finished reading it)
        if (p + 1 < PHASES) {
            char* bufn = lbuf[(p & 1) ^ 1];
            const size_t go = (size_t)(2 * p + 2) * 4096;
            gld16(gh + go + (size_t)tid * 16, bufn + tid * 16);
            gld16(gl + go + (size_t)tid * 16, bufn + 4096 + tid * 16);
            gld16(gh + go + 4096 + (size_t)tid * 16, bufn + 8192 + tid * 16);
            gld16(gl + go + 4096 + (size_t)tid * 16, bufn + 12288 + tid * 16);
        }
        const float nsq0 = nsqA, nsq1 = nsqB;
        if (p + 1 < PHASES) {
            nsqA = -psq[(2 * p + 2) * 32];
            nsqB = -psq[(2 * p + 3) * 32];
        }

        SUBTILE(bufc, bufc + 4096, nsq0, (c0 + 2 * p) * 32 + col);
        SUBTILE(bufc + 8192, bufc + 12288, nsq1, (c0 + 2 * p + 1) * 32 + col);

        // single per-phase sync: drain this phase's prefetch (issued ~48
        // MFMAs ago -> latency hidden), then release buffers to all waves.
        asm volatile("s_waitcnt vmcnt(0)" ::: "memory");
        __builtin_amdgcn_s_barrier();
        asm volatile("" ::: "memory");
    }

    // C/D layout (32x32): col = lane&31, row = (r&3) + 8*(r>>2) + 4*half_.
    // Slot r<16 -> row group 0, r>=16 -> +32.
#pragma unroll
    for (int r = 0; r < 32; ++r) {
        float bv = best[r];
        int bi = bidx[r];
#pragma unroll
        for (int d = 1; d < 32; d <<= 1) {
            float ov = __shfl_xor(bv, d);
            int oi = __shfl_xor(bi, d);
            if (ov > bv || (ov == bv && oi < bi)) {  // smaller idx on tie
                bv = ov;
                bi = oi;
            }
        }
        if (col == 0) {
            const int rr = r & 15;
            const int row = row_base + (r >> 4) * 32 + (rr & 3) +
                            8 * (rr >> 2) + 4 * half_;
            // monotone f32 -> u32 map (order-preserving incl. negatives)
            unsigned ub = __float_as_uint(bv);
            unsigned mapped = ub ^ (((int)ub >> 31) | 0x80000000u);
            unsigned long long key =
                ((unsigned long long)mapped << 32) | (unsigned)(~bi);
            atomicMax(keys + row, key);  // equal dist -> larger ~bi = min bi
        }
    }
}

// ---------------------------------------------------------------------------
// Kernel 2: read per-row key, gather quantize row, write index-as-float.
// One thread per (row, float4-chunk): t in [0, N_ROWS*16).
// ---------------------------------------------------------------------------
__global__ void combine_kernel(const unsigned long long* __restrict__ keys,
                               const float* __restrict__ embed,
                               float* __restrict__ out) {
    const int t = blockIdx.x * blockDim.x + threadIdx.x;
    const int row = t >> 4;
    const int q = t & 15;
    if (row >= N_ROWS) return;

    const unsigned long long key = keys[row];
    const int bi = (int)(~(unsigned)key);  // low32 stored as ~idx

    const float4* e4 = reinterpret_cast<const float4*>(embed);
    float4 v = e4[(size_t)bi * (DIM / 4) + q];
    reinterpret_cast<float4*>(out)[(size_t)row * (DIM / 4) + q] = v;
    if (q == 0) {
        out[(size_t)QUANT_ELEMS + row] = (float)bi;  // index as float
    }
}

// ---------------------------------------------------------------------------
extern "C" void kernel_launch(void* const* d_in, const int* in_sizes, int n_in,
                              void* d_out, int out_size, void* d_ws,
                              size_t ws_size, hipStream_t stream) {
    const float* x = (const float*)d_in[0];
    const float* embed = (const float*)d_in[1];
    float* out = (float*)d_out;

    // ws: sq 16KB | ehi 512KB | elo 512KB | keys 256KB   (total ~1.28 MB)
    char* ws = (char*)d_ws;
    float* sq = (float*)ws;
    half8* ehi = (half8*)(ws + 16384);
    half8* elo = (half8*)(ws + 16384 + 524288);
    unsigned long long* keys =
        (unsigned long long*)(ws + 16384 + 2 * 524288);

    prep_kernel<<<TILES_TOTAL, 256, 0, stream>>>(embed, sq, ehi, elo, keys);

    dim3 grid(N_ROWS / 256, SPLITS);
    fused_dist_argmax64<<<grid, 256, 0, stream>>>(x, sq, ehi, elo, keys);

    const int combine_threads = N_ROWS * (DIM / 4);
    combine_kernel<<<(combine_threads + 255) / 256, 256, 0, stream>>>(
        keys, embed, out);
}

// Round 7
// 139.907 us; speedup vs baseline: 2.8763x; 1.8198x over previous
//
#include <hip/hip_runtime.h>
#include <math.h>

#define N_ROWS 32768
#define K_CODES 4096
#define DIM 64
#define SPLITS 8
#define TILES_TOTAL (K_CODES / 32)              // 128
#define TILES_PER_SPLIT (TILES_TOTAL / SPLITS)  // 16 (fits a 4-bit nibble)
#define PHASES (TILES_PER_SPLIT / 2)            // 8 (2 tiles per phase)
#define QUANT_ELEMS (N_ROWS * DIM)              // 2097152

typedef _Float16 half8 __attribute__((ext_vector_type(8)));
typedef float floatx16 __attribute__((ext_vector_type(16)));

// async global->LDS, 16 B per lane (wave-uniform base + lane*16 layout)
__device__ __forceinline__ void gld16(const void* g, void* l) {
    __builtin_amdgcn_global_load_lds(
        (const __attribute__((address_space(1))) unsigned int*)g,
        (__attribute__((address_space(3))) unsigned int*)l, 16, 0, 0);
}

// ---------------------------------------------------------------------------
// Kernel 0 (fused): embed -> fp16 hi/lo B-fragments for mfma_f32_32x32x16_f16
// AND per-code squared norms (LDS reduction) AND zero-init of the per-row
// argmax keys (grid is exactly N_ROWS threads).
// Tile c = 32 codes; kstep s covers k=16s..16s+15. Thread t = c*256 + s*64 + l
// holds B[k=(l>>5)*8+j+16s][col=l&31] = embed[c*32+(l&31)][(l>>5)*8+j+16s].
// One 256-thread block per tile (grid = 128 blocks).
// ---------------------------------------------------------------------------
__global__ void prep_kernel(const float* __restrict__ embed,
                            float* __restrict__ sq, half8* __restrict__ ehi,
                            half8* __restrict__ elo,
                            unsigned long long* __restrict__ keys) {
    __shared__ float part[256];
    const int tid = threadIdx.x;
    const int t = blockIdx.x * 256 + tid;
    keys[t] = 0ull;  // any finite packed key beats 0
    const int l = t & 63;
    const int s = (t >> 6) & 3;
    const int c = blockIdx.x;  // == t >> 8
    const int col = l & 31;
    const int code = c * 32 + col;
    const int koff = (l >> 5) * 8 + 16 * s;
    const float* src = embed + (size_t)code * DIM + koff;
    half8 h, lo;
    float ss = 0.f;
#pragma unroll
    for (int j = 0; j < 8; ++j) {
        float v = src[j];
        ss = fmaf(v, v, ss);
        _Float16 hi = (_Float16)v;
        h[j] = hi;
        lo[j] = (_Float16)(v - (float)hi);
    }
    ehi[t] = h;
    elo[t] = lo;
    part[tid] = ss;
    __syncthreads();
    if (tid < 32) {
        // code (c*32 + tid)'s 8 partials live at tid + 32*h + 64*s
        float a = 0.f;
#pragma unroll
        for (int q = 0; q < 8; ++q) a += part[tid + 32 * (q & 1) + 64 * (q >> 1)];
        sq[c * 32 + tid] = a;
    }
}

// ---------------------------------------------------------------------------
// Kernel 1: fused dist(GEMM 32x32x16) + per-split argmax.
// v7 = M=64 register blocking with NIBBLE-PACKED tile indices.
// Register accounting (the v5/v6 spill killer): ah/al 64 + acc 32 +
// best[32] 32 + pk[4] 4 + temps ~14 = ~146 <= 168 cap of (256,3).
// bidx[32] (64 regs) is replaced by pk[4]: tile-in-split is 0..15 = 4 bits
// per slot; index reconstructed in the epilogue as (c0+nib)*32+col.
// Each B ds_read_b128 feeds 6 MFMAs -> LDS demand 10.3us vs MFMA 20.6us/CU.
// SPLITS=8 -> grid (128,8)=1024 blocks -> 3 blocks/CU resident (12 waves).
// Double-buffered 16 KB LDS phases (2 tiles/phase), prefetch-before-compute,
// one {s_waitcnt vmcnt(0); s_barrier} per phase.
// Cross-split/cross-wave argmax combine via packed-key atomicMax:
// key = monotone_u32(dist) << 32 | ~idx  (equal dist -> smaller idx wins,
// matching reference first-match tie semantics exactly; proven in v6).
// dist = dot(2x,e) - ||e||^2 ; -||e||^2 = acc init, 2x folded into A (exact).
// fp16 split, 3 terms: xh*eh + xl*eh + xh*el.
// ---------------------------------------------------------------------------
#define SUBTILE(LH, LL, NSQ, CT)                                             \
    {                                                                        \
        const half8* lh = (const half8*)(LH);                                \
        const half8* ll = (const half8*)(LL);                                \
        floatx16 a0, a1;                                                     \
        _Pragma("unroll") for (int r = 0; r < 16; ++r) {                     \
            a0[r] = (NSQ);                                                   \
            a1[r] = (NSQ);                                                   \
        }                                                                    \
        half8 b;                                                             \
        __builtin_amdgcn_s_setprio(1);                                       \
        b = lh[lane];                                                        \
        a0 = __builtin_amdgcn_mfma_f32_32x32x16_f16(ah[0], b, a0, 0, 0, 0);  \
        a1 = __builtin_amdgcn_mfma_f32_32x32x16_f16(ah[4], b, a1, 0, 0, 0);  \
        a0 = __builtin_amdgcn_mfma_f32_32x32x16_f16(al[0], b, a0, 0, 0, 0);  \
        a1 = __builtin_amdgcn_mfma_f32_32x32x16_f16(al[4], b, a1, 0, 0, 0);  \
        b = lh[64 + lane];                                                   \
        a0 = __builtin_amdgcn_mfma_f32_32x32x16_f16(ah[1], b, a0, 0, 0, 0);  \
        a1 = __builtin_amdgcn_mfma_f32_32x32x16_f16(ah[5], b, a1, 0, 0, 0);  \
        a0 = __builtin_amdgcn_mfma_f32_32x32x16_f16(al[1], b, a0, 0, 0, 0);  \
        a1 = __builtin_amdgcn_mfma_f32_32x32x16_f16(al[5], b, a1, 0, 0, 0);  \
        b = lh[128 + lane];                                                  \
        a0 = __builtin_amdgcn_mfma_f32_32x32x16_f16(ah[2], b, a0, 0, 0, 0);  \
        a1 = __builtin_amdgcn_mfma_f32_32x32x16_f16(ah[6], b, a1, 0, 0, 0);  \
        a0 = __builtin_amdgcn_mfma_f32_32x32x16_f16(al[2], b, a0, 0, 0, 0);  \
        a1 = __builtin_amdgcn_mfma_f32_32x32x16_f16(al[6], b, a1, 0, 0, 0);  \
        b = lh[192 + lane];                                                  \
        a0 = __builtin_amdgcn_mfma_f32_32x32x16_f16(ah[3], b, a0, 0, 0, 0);  \
        a1 = __builtin_amdgcn_mfma_f32_32x32x16_f16(ah[7], b, a1, 0, 0, 0);  \
        a0 = __builtin_amdgcn_mfma_f32_32x32x16_f16(al[3], b, a0, 0, 0, 0);  \
        a1 = __builtin_amdgcn_mfma_f32_32x32x16_f16(al[7], b, a1, 0, 0, 0);  \
        b = ll[lane];                                                        \
        a0 = __builtin_amdgcn_mfma_f32_32x32x16_f16(ah[0], b, a0, 0, 0, 0);  \
        a1 = __builtin_amdgcn_mfma_f32_32x32x16_f16(ah[4], b, a1, 0, 0, 0);  \
        b = ll[64 + lane];                                                   \
        a0 = __builtin_amdgcn_mfma_f32_32x32x16_f16(ah[1], b, a0, 0, 0, 0);  \
        a1 = __builtin_amdgcn_mfma_f32_32x32x16_f16(ah[5], b, a1, 0, 0, 0);  \
        b = ll[128 + lane];                                                  \
        a0 = __builtin_amdgcn_mfma_f32_32x32x16_f16(ah[2], b, a0, 0, 0, 0);  \
        a1 = __builtin_amdgcn_mfma_f32_32x32x16_f16(ah[6], b, a1, 0, 0, 0);  \
        b = ll[192 + lane];                                                  \
        a0 = __builtin_amdgcn_mfma_f32_32x32x16_f16(ah[3], b, a0, 0, 0, 0);  \
        a1 = __builtin_amdgcn_mfma_f32_32x32x16_f16(ah[7], b, a1, 0, 0, 0);  \
        __builtin_amdgcn_s_setprio(0);                                       \
        const unsigned ctu = (unsigned)(CT);                                 \
        _Pragma("unroll") for (int r = 0; r < 16; ++r) {                     \
            const int sh = (r & 7) * 4; /* compile-time */                   \
            if (a0[r] > best[r]) { /* strict >: earliest tile wins ties */   \
                best[r] = a0[r];                                             \
                pk[r >> 3] =                                                 \
                    (pk[r >> 3] & ~(0xFu << sh)) | (ctu << sh);              \
            }                                                                \
            if (a1[r] > best[16 + r]) {                                      \
                best[16 + r] = a1[r];                                        \
                pk[2 + (r >> 3)] =                                           \
                    (pk[2 + (r >> 3)] & ~(0xFu << sh)) | (ctu << sh);        \
            }                                                                \
        }                                                                    \
    }

__global__ __launch_bounds__(256, 3) void fused_dist_argmax64(
    const float* __restrict__ x, const float* __restrict__ sq,
    const half8* __restrict__ ehi, const half8* __restrict__ elo,
    unsigned long long* __restrict__ keys) {
    // two 16 KB phase buffers; within a buffer:
    // [0,4K)=hi(tile 2p) [4K,8K)=lo(2p) [8K,12K)=hi(2p+1) [12K,16K)=lo(2p+1)
    __shared__ __align__(16) char lbuf[2][16384];
    const int tid = threadIdx.x;
    const int lane = tid & 63;
    const int wave = tid >> 6;
    const int col = lane & 31;    // B col (code within tile); A row within group
    const int half_ = lane >> 5;  // k-half
    const int row_base = blockIdx.x * 256 + wave * 64;
    const int split = blockIdx.y;
    const int c0 = split * TILES_PER_SPLIT;

    // Persistent A fragments (scaled by 2), two 32-row groups:
    // group g rows = row_base + g*32 + col; A[m=col][k=half_*8+j+16s]
    half8 ah[8], al[8];
#pragma unroll
    for (int g = 0; g < 2; ++g) {
        const float* xs =
            x + (size_t)(row_base + g * 32 + col) * DIM + half_ * 8;
#pragma unroll
        for (int s = 0; s < 4; ++s) {
            half8 h, lo;
#pragma unroll
            for (int j = 0; j < 8; ++j) {
                float v = 2.0f * xs[16 * s + j];
                _Float16 hi = (_Float16)v;
                h[j] = hi;
                lo[j] = (_Float16)(v - (float)hi);
            }
            ah[g * 4 + s] = h;
            al[g * 4 + s] = lo;
        }
    }

    float best[32];
    unsigned pk[4];  // 4-bit tile-in-split index per slot (32 slots)
#pragma unroll
    for (int r = 0; r < 32; ++r) best[r] = -INFINITY;
#pragma unroll
    for (int r = 0; r < 4; ++r) pk[r] = 0u;

    const char* gh = (const char*)(ehi + (size_t)c0 * 256);
    const char* gl = (const char*)(elo + (size_t)c0 * 256);
    const float* psq = sq + c0 * 32 + col;

    // --- prologue: stage phase 0 (tiles 0,1) into lbuf[0] ---
    {
        char* d = lbuf[0];
        gld16(gh + (size_t)tid * 16, d + tid * 16);
        gld16(gl + (size_t)tid * 16, d + 4096 + tid * 16);
        gld16(gh + 4096 + (size_t)tid * 16, d + 8192 + tid * 16);
        gld16(gl + 4096 + (size_t)tid * 16, d + 12288 + tid * 16);
    }
    float nsqA = -psq[0];
    float nsqB = -psq[32];
    asm volatile("s_waitcnt vmcnt(0)" ::: "memory");
    __builtin_amdgcn_s_barrier();
    asm volatile("" ::: "memory");

    for (int p = 0; p < PHASES; ++p) {
        char* bufc = lbuf[p & 1];
        // prefetch phase p+1 into the other buffer (safe: barrier at end of
        // phase p-1 guarantees all waves finished reading it)
        if (p + 1 < PHASES) {
            char* bufn = lbuf[(p & 1) ^ 1];
            const size_t go = (size_t)(2 * p + 2) * 4096;
            gld16(gh + go + (size_t)tid * 16, bufn + tid * 16);
            gld16(gl + go + (size_t)tid * 16, bufn + 4096 + tid * 16);
            gld16(gh + go + 4096 + (size_t)tid * 16, bufn + 8192 + tid * 16);
            gld16(gl + go + 4096 + (size_t)tid * 16, bufn + 12288 + tid * 16);
        }
        const float nsq0 = nsqA, nsq1 = nsqB;
        if (p + 1 < PHASES) {
            nsqA = -psq[(2 * p + 2) * 32];
            nsqB = -psq[(2 * p + 3) * 32];
        }

        SUBTILE(bufc, bufc + 4096, nsq0, 2 * p);
        SUBTILE(bufc + 8192, bufc + 12288, nsq1, 2 * p + 1);

        // single per-phase sync: drain this phase's prefetch (issued ~48
        // MFMAs ago -> latency hidden), then release buffers to all waves.
        asm volatile("s_waitcnt vmcnt(0)" ::: "memory");
        __builtin_amdgcn_s_barrier();
        asm volatile("" ::: "memory");
    }

    // C/D layout (32x32): col = lane&31, row = (r&3) + 8*(r>>2) + 4*half_.
    // Slot r<16 -> row group 0, r>=16 -> +32. Tile idx from pk nibbles.
#pragma unroll
    for (int r = 0; r < 32; ++r) {
        float bv = best[r];
        const int tr = (int)((pk[r >> 3] >> ((r & 7) * 4)) & 0xFu);
        int bi = (c0 + tr) * 32 + col;
#pragma unroll
        for (int d = 1; d < 32; d <<= 1) {
            float ov = __shfl_xor(bv, d);
            int oi = __shfl_xor(bi, d);
            if (ov > bv || (ov == bv && oi < bi)) {  // smaller idx on tie
                bv = ov;
                bi = oi;
            }
        }
        if (col == 0) {
            const int rr = r & 15;
            const int row = row_base + (r >> 4) * 32 + (rr & 3) +
                            8 * (rr >> 2) + 4 * half_;
            // monotone f32 -> u32 map (order-preserving incl. negatives)
            unsigned ub = __float_as_uint(bv);
            unsigned mapped = ub ^ (((int)ub >> 31) | 0x80000000u);
            unsigned long long key =
                ((unsigned long long)mapped << 32) | (unsigned)(~bi);
            atomicMax(keys + row, key);  // equal dist -> larger ~bi = min bi
        }
    }
}

// ---------------------------------------------------------------------------
// Kernel 2: read per-row key, gather quantize row, write index-as-float.
// One thread per (row, float4-chunk): t in [0, N_ROWS*16).
// ---------------------------------------------------------------------------
__global__ void combine_kernel(const unsigned long long* __restrict__ keys,
                               const float* __restrict__ embed,
                               float* __restrict__ out) {
    const int t = blockIdx.x * blockDim.x + threadIdx.x;
    const int row = t >> 4;
    const int q = t & 15;
    if (row >= N_ROWS) return;

    const unsigned long long key = keys[row];
    const int bi = (int)(~(unsigned)key);  // low32 stored as ~idx

    const float4* e4 = reinterpret_cast<const float4*>(embed);
    float4 v = e4[(size_t)bi * (DIM / 4) + q];
    reinterpret_cast<float4*>(out)[(size_t)row * (DIM / 4) + q] = v;
    if (q == 0) {
        out[(size_t)QUANT_ELEMS + row] = (float)bi;  // index as float
    }
}

// ---------------------------------------------------------------------------
extern "C" void kernel_launch(void* const* d_in, const int* in_sizes, int n_in,
                              void* d_out, int out_size, void* d_ws,
                              size_t ws_size, hipStream_t stream) {
    const float* x = (const float*)d_in[0];
    const float* embed = (const float*)d_in[1];
    float* out = (float*)d_out;

    // ws: sq 16KB | ehi 512KB | elo 512KB | keys 256KB   (total ~1.28 MB)
    char* ws = (char*)d_ws;
    float* sq = (float*)ws;
    half8* ehi = (half8*)(ws + 16384);
    half8* elo = (half8*)(ws + 16384 + 524288);
    unsigned long long* keys =
        (unsigned long long*)(ws + 16384 + 2 * 524288);

    prep_kernel<<<TILES_TOTAL, 256, 0, stream>>>(embed, sq, ehi, elo, keys);

    dim3 grid(N_ROWS / 256, SPLITS);
    fused_dist_argmax64<<<grid, 256, 0, stream>>>(x, sq, ehi, elo, keys);

    const int combine_threads = N_ROWS * (DIM / 4);
    combine_kernel<<<(combine_threads + 255) / 256, 256, 0, stream>>>(
        keys, embed, out);
}

// Round 8
// 123.313 us; speedup vs baseline: 3.2633x; 1.1346x over previous
//
#include <hip/hip_runtime.h>
#include <math.h>

#define N_ROWS 32768
#define K_CODES 4096
#define DIM 64
#define SPLITS 4
#define TILES_TOTAL (K_CODES / 32)              // 128
#define TILES_PER_SPLIT (TILES_TOTAL / SPLITS)  // 32
#define PHASES (TILES_PER_SPLIT / 2)            // 16 (2 tiles per phase)
#define QUANT_ELEMS (N_ROWS * DIM)              // 2097152

typedef _Float16 half8 __attribute__((ext_vector_type(8)));
typedef float floatx16 __attribute__((ext_vector_type(16)));

// async global->LDS, 16 B per lane (wave-uniform base + lane*16 layout)
__device__ __forceinline__ void gld16(const void* g, void* l) {
    __builtin_amdgcn_global_load_lds(
        (const __attribute__((address_space(1))) unsigned int*)g,
        (__attribute__((address_space(3))) unsigned int*)l, 16, 0, 0);
}

// ---------------------------------------------------------------------------
// Kernel 0 (fused): embed -> fp16 hi/lo B-fragments for mfma_f32_32x32x16_f16
// AND per-code squared norms (LDS reduction) AND zero-init of the per-row
// argmax keys (grid is exactly N_ROWS threads).
// Tile c = 32 codes; kstep s covers k=16s..16s+15. Thread t = c*256 + s*64 + l
// holds B[k=(l>>5)*8+j+16s][col=l&31] = embed[c*32+(l&31)][(l>>5)*8+j+16s].
// One 256-thread block per tile (grid = 128 blocks).
// ---------------------------------------------------------------------------
__global__ void prep_kernel(const float* __restrict__ embed,
                            float* __restrict__ sq, half8* __restrict__ ehi,
                            half8* __restrict__ elo,
                            unsigned long long* __restrict__ keys) {
    __shared__ float part[256];
    const int tid = threadIdx.x;
    const int t = blockIdx.x * 256 + tid;
    keys[t] = 0ull;  // any finite packed key beats 0
    const int l = t & 63;
    const int s = (t >> 6) & 3;
    const int c = blockIdx.x;  // == t >> 8
    const int col = l & 31;
    const int code = c * 32 + col;
    const int koff = (l >> 5) * 8 + 16 * s;
    const float* src = embed + (size_t)code * DIM + koff;
    half8 h, lo;
    float ss = 0.f;
#pragma unroll
    for (int j = 0; j < 8; ++j) {
        float v = src[j];
        ss = fmaf(v, v, ss);
        _Float16 hi = (_Float16)v;
        h[j] = hi;
        lo[j] = (_Float16)(v - (float)hi);
    }
    ehi[t] = h;
    elo[t] = lo;
    part[tid] = ss;
    __syncthreads();
    if (tid < 32) {
        // code (c*32 + tid)'s 8 partials live at tid + 32*h + 64*s
        float a = 0.f;
#pragma unroll
        for (int q = 0; q < 8; ++q) a += part[tid + 32 * (q & 1) + 64 * (q >> 1)];
        sq[c * 32 + tid] = a;
    }
}

// ---------------------------------------------------------------------------
// Kernel 1: fused dist(GEMM 32x32x16) + per-split argmax.
// v8 = v2 base (M=32, 16 waves/CU, 62us, spill-free) + ENTRY TIME-STAGGER.
// Diagnosis across v2/v4/v7: dur ~= SUM of pipe demands (MFMA 20.6us +
// LDS-read 20.5us + VALU ~7us per CU) because co-resident blocks run
// IDENTICAL per-phase schedules launched simultaneously -> accidental
// phase-lock: all waves burst ds_read together, then all MFMA together.
// Fix: offset co-resident blocks by k*~960 cyc (k=0..3). Offsets persist
// (equal phase durations) -> the 4 blocks spread across the phase cycle and
// LDS/MFMA/VALU bursts interleave. Cost: <=1.2us tail.
// Stagger key (bx+by)&3 covers both consecutive and stride-256 co-residency.
// dist = dot(2x,e) - ||e||^2 ; -||e||^2 = acc init, 2x folded into A (exact).
// fp16 split, 3 terms: xh*eh + xl*eh + xh*el.
// grid = (N_ROWS/128, SPLITS) = (256, 4), block = 256 (4 waves x 32 rows).
// Cross-split/cross-wave argmax combine via packed-key atomicMax (exact tie
// semantics, validated in v7).
// ---------------------------------------------------------------------------
__global__ __launch_bounds__(256, 4) void fused_dist_argmax32(
    const float* __restrict__ x, const float* __restrict__ sq,
    const half8* __restrict__ ehi, const half8* __restrict__ elo,
    unsigned long long* __restrict__ keys) {
    // two 16 KB phase buffers; within a buffer:
    // [0,4K)=hi(tile 2p) [4K,8K)=lo(2p) [8K,12K)=hi(2p+1) [12K,16K)=lo(2p+1)
    __shared__ __align__(16) char lbuf[2][16384];

    // --- entry de-phasing: break cross-block phase-lock ---
    {
        const int stag = (blockIdx.x + blockIdx.y) & 3;
        if (stag > 0) __builtin_amdgcn_s_sleep(15);  // ~960 cyc each
        if (stag > 1) __builtin_amdgcn_s_sleep(15);
        if (stag > 2) __builtin_amdgcn_s_sleep(15);
    }

    const int tid = threadIdx.x;
    const int lane = tid & 63;
    const int wave = tid >> 6;
    const int col = lane & 31;    // B col (code within tile); A row
    const int half_ = lane >> 5;  // k-half
    const int row_base = blockIdx.x * 128 + wave * 32;
    const int split = blockIdx.y;
    const int c0 = split * TILES_PER_SPLIT;

    // Persistent A fragments (scaled by 2): A[m=col][k=half_*8+j+16s]
    half8 ah[4], al[4];
    {
        const float* xs = x + (size_t)(row_base + col) * DIM + half_ * 8;
#pragma unroll
        for (int s = 0; s < 4; ++s) {
            half8 h, lo;
#pragma unroll
            for (int j = 0; j < 8; ++j) {
                float v = 2.0f * xs[16 * s + j];
                _Float16 hi = (_Float16)v;
                h[j] = hi;
                lo[j] = (_Float16)(v - (float)hi);
            }
            ah[s] = h;
            al[s] = lo;
        }
    }

    float best[16];
    int bidx[16];
#pragma unroll
    for (int r = 0; r < 16; ++r) {
        best[r] = -INFINITY;
        bidx[r] = 0;
    }

    const char* gh = (const char*)(ehi + (size_t)c0 * 256);
    const char* gl = (const char*)(elo + (size_t)c0 * 256);
    const float* psq = sq + c0 * 32 + col;
    const half8* lh0 = (const half8*)lbuf[0];
    const half8* ll0 = (const half8*)(lbuf[0] + 4096);

    // --- prologue: stage phase 0 (tiles 0,1) into lbuf[0] ---
    {
        char* d = lbuf[0];
        gld16(gh + (size_t)tid * 16, d + tid * 16);
        gld16(gl + (size_t)tid * 16, d + 4096 + tid * 16);
        gld16(gh + 4096 + (size_t)tid * 16, d + 8192 + tid * 16);
        gld16(gl + 4096 + (size_t)tid * 16, d + 12288 + tid * 16);
    }
    float nsqA = -psq[0];
    float nsqB = -psq[32];
    asm volatile("s_waitcnt vmcnt(0)" ::: "memory");
    __builtin_amdgcn_s_barrier();
    asm volatile("" ::: "memory");

#define SUBTILE(LH, LL, NSQ, CIDX)                                            \
    {                                                                         \
        const half8* lh = (const half8*)(LH);                                 \
        const half8* ll = (const half8*)(LL);                                 \
        floatx16 acc;                                                         \
        _Pragma("unroll") for (int r = 0; r < 16; ++r) acc[r] = (NSQ);        \
        half8 b;                                                              \
        __builtin_amdgcn_s_setprio(1);                                        \
        b = lh[lane];                                                         \
        acc = __builtin_amdgcn_mfma_f32_32x32x16_f16(ah[0], b, acc, 0, 0, 0); \
        acc = __builtin_amdgcn_mfma_f32_32x32x16_f16(al[0], b, acc, 0, 0, 0); \
        b = lh[64 + lane];                                                    \
        acc = __builtin_amdgcn_mfma_f32_32x32x16_f16(ah[1], b, acc, 0, 0, 0); \
        acc = __builtin_amdgcn_mfma_f32_32x32x16_f16(al[1], b, acc, 0, 0, 0); \
        b = lh[128 + lane];                                                   \
        acc = __builtin_amdgcn_mfma_f32_32x32x16_f16(ah[2], b, acc, 0, 0, 0); \
        acc = __builtin_amdgcn_mfma_f32_32x32x16_f16(al[2], b, acc, 0, 0, 0); \
        b = lh[192 + lane];                                                   \
        acc = __builtin_amdgcn_mfma_f32_32x32x16_f16(ah[3], b, acc, 0, 0, 0); \
        acc = __builtin_amdgcn_mfma_f32_32x32x16_f16(al[3], b, acc, 0, 0, 0); \
        b = ll[lane];                                                         \
        acc = __builtin_amdgcn_mfma_f32_32x32x16_f16(ah[0], b, acc, 0, 0, 0); \
        b = ll[64 + lane];                                                    \
        acc = __builtin_amdgcn_mfma_f32_32x32x16_f16(ah[1], b, acc, 0, 0, 0); \
        b = ll[128 + lane];                                                   \
        acc = __builtin_amdgcn_mfma_f32_32x32x16_f16(ah[2], b, acc, 0, 0, 0); \
        b = ll[192 + lane];                                                   \
        acc = __builtin_amdgcn_mfma_f32_32x32x16_f16(ah[3], b, acc, 0, 0, 0); \
        __builtin_amdgcn_s_setprio(0);                                        \
        const int cidx = (CIDX);                                              \
        _Pragma("unroll") for (int r = 0; r < 16; ++r) {                      \
            if (acc[r] > best[r]) { /* strict >: earliest tile wins ties */   \
                best[r] = acc[r];                                             \
                bidx[r] = cidx;                                               \
            }                                                                 \
        }                                                                     \
    }

    for (int p = 0; p < PHASES; ++p) {
        char* bufc = lbuf[p & 1];
        // prefetch phase p+1 into the other buffer (safe: barrier at end of
        // phase p-1 guarantees all waves finished reading it)
        if (p + 1 < PHASES) {
            char* bufn = lbuf[(p & 1) ^ 1];
            const size_t go = (size_t)(2 * p + 2) * 4096;
            gld16(gh + go + (size_t)tid * 16, bufn + tid * 16);
            gld16(gl + go + (size_t)tid * 16, bufn + 4096 + tid * 16);
            gld16(gh + go + 4096 + (size_t)tid * 16, bufn + 8192 + tid * 16);
            gld16(gl + go + 4096 + (size_t)tid * 16, bufn + 12288 + tid * 16);
        }
        const float nsq0 = nsqA, nsq1 = nsqB;
        if (p + 1 < PHASES) {
            nsqA = -psq[(2 * p + 2) * 32];
            nsqB = -psq[(2 * p + 3) * 32];
        }

        SUBTILE(bufc, bufc + 4096, nsq0, (c0 + 2 * p) * 32 + col);
        SUBTILE(bufc + 8192, bufc + 12288, nsq1, (c0 + 2 * p + 1) * 32 + col);

        // single per-phase sync: drain this phase's prefetch (issued ~24
        // MFMAs ago -> latency hidden), then release buffers to all waves.
        asm volatile("s_waitcnt vmcnt(0)" ::: "memory");
        __builtin_amdgcn_s_barrier();
        asm volatile("" ::: "memory");
    }

    // C/D layout (32x32): col = lane&31, row = (r&3) + 8*(r>>2) + 4*half_.
#pragma unroll
    for (int r = 0; r < 16; ++r) {
        float bv = best[r];
        int bi = bidx[r];
#pragma unroll
        for (int d = 1; d < 32; d <<= 1) {
            float ov = __shfl_xor(bv, d);
            int oi = __shfl_xor(bi, d);
            if (ov > bv || (ov == bv && oi < bi)) {  // smaller idx on tie
                bv = ov;
                bi = oi;
            }
        }
        if (col == 0) {
            const int row = row_base + (r & 3) + 8 * (r >> 2) + 4 * half_;
            // monotone f32 -> u32 map (order-preserving incl. negatives)
            unsigned ub = __float_as_uint(bv);
            unsigned mapped = ub ^ (((int)ub >> 31) | 0x80000000u);
            unsigned long long key =
                ((unsigned long long)mapped << 32) | (unsigned)(~bi);
            atomicMax(keys + row, key);  // equal dist -> larger ~bi = min bi
        }
    }
#undef SUBTILE
}

// ---------------------------------------------------------------------------
// Kernel 2: read per-row key, gather quantize row, write index-as-float.
// One thread per (row, float4-chunk): t in [0, N_ROWS*16).
// ---------------------------------------------------------------------------
__global__ void combine_kernel(const unsigned long long* __restrict__ keys,
                               const float* __restrict__ embed,
                               float* __restrict__ out) {
    const int t = blockIdx.x * blockDim.x + threadIdx.x;
    const int row = t >> 4;
    const int q = t & 15;
    if (row >= N_ROWS) return;

    const unsigned long long key = keys[row];
    const int bi = (int)(~(unsigned)key);  // low32 stored as ~idx

    const float4* e4 = reinterpret_cast<const float4*>(embed);
    float4 v = e4[(size_t)bi * (DIM / 4) + q];
    reinterpret_cast<float4*>(out)[(size_t)row * (DIM / 4) + q] = v;
    if (q == 0) {
        out[(size_t)QUANT_ELEMS + row] = (float)bi;  // index as float
    }
}

// ---------------------------------------------------------------------------
extern "C" void kernel_launch(void* const* d_in, const int* in_sizes, int n_in,
                              void* d_out, int out_size, void* d_ws,
                              size_t ws_size, hipStream_t stream) {
    const float* x = (const float*)d_in[0];
    const float* embed = (const float*)d_in[1];
    float* out = (float*)d_out;

    // ws: sq 16KB | ehi 512KB | elo 512KB | keys 256KB   (total ~1.28 MB)
    char* ws = (char*)d_ws;
    float* sq = (float*)ws;
    half8* ehi = (half8*)(ws + 16384);
    half8* elo = (half8*)(ws + 16384 + 524288);
    unsigned long long* keys =
        (unsigned long long*)(ws + 16384 + 2 * 524288);

    prep_kernel<<<TILES_TOTAL, 256, 0, stream>>>(embed, sq, ehi, elo, keys);

    dim3 grid(N_ROWS / 128, SPLITS);
    fused_dist_argmax32<<<grid, 256, 0, stream>>>(x, sq, ehi, elo, keys);

    const int combine_threads = N_ROWS * (DIM / 4);
    combine_kernel<<<(combine_threads + 255) / 256, 256, 0, stream>>>(
        keys, embed, out);
}